// Round 6
// baseline (783.533 us; speedup 1.0000x reference)
//
#include <hip/hip_runtime.h>

typedef unsigned short ushort_t;
typedef unsigned int u32;
typedef float f32x4 __attribute__((ext_vector_type(4)));
typedef short s16x8 __attribute__((ext_vector_type(8)));

#define BROWS 4096
#define DIMK  1024
#define RANKK 256
#define TROWS 16
#define GPAD  264      // gb row pad: 264 us = 528 B (16B-aligned rows)
#define XPAD  1028     // xs row pad: 1028 f32 (breaks 32-bank aliasing)

#define DTF 0.01f
#define THETAF 1.35120719195965763f
#define C1F    0.675603595979828816f   // THETA/2
#define C2F   (-0.175603595979828816f) // (1-THETA)/2
#define D1F    1.35120719195965763f    // THETA
#define D2F   (-1.70241438391931526f)  // 1-2*THETA

__device__ __forceinline__ ushort_t f2bf(float f) {
    unsigned u = __builtin_bit_cast(unsigned, f);
    return (ushort_t)((u + 0x7FFFu + ((u >> 16) & 1u)) >> 16);
}
__device__ __forceinline__ u32 pack2bf(float lo, float hi) {
    return (u32)f2bf(lo) | ((u32)f2bf(hi) << 16);
}
__device__ __forceinline__ float unpk_lo(u32 u) {
    return __builtin_bit_cast(float, u << 16);
}
__device__ __forceinline__ float unpk_hi(u32 u) {
    return __builtin_bit_cast(float, u & 0xFFFF0000u);
}

// ---------------------------------------------------------------------------
// Transpose + cast f32 -> bf16:  out[c][r] = bf16(in[r][c]),  in is [R][C].
// ---------------------------------------------------------------------------
__global__ void fr_transpose_cast(const float* __restrict__ in,
                                  ushort_t* __restrict__ out, int R, int C) {
    __shared__ float tile[32][33];
    int tiles_c = C >> 5;
    int tr = blockIdx.x / tiles_c;
    int tc = blockIdx.x % tiles_c;
    int tx = threadIdx.x & 31;
    int ty = threadIdx.x >> 5;
#pragma unroll
    for (int i = 0; i < 32; i += 8)
        tile[ty + i][tx] = in[(size_t)(tr * 32 + ty + i) * C + tc * 32 + tx];
    __syncthreads();
#pragma unroll
    for (int i = 0; i < 32; i += 8)
        out[(size_t)(tc * 32 + ty + i) * R + tr * 32 + tx] = f2bf(tile[tx][ty + i]);
}

// ---------------------------------------------------------------------------
// Fused Forest-Ruth integrator. Block = 16 rows, 512 threads (8 waves).
// Per-lane 16B B-fragment loads (L2-resident) with a 4-buffer x 4-load
// rotating register prefetch (12-16 loads in flight, issue-to-use ~4 groups).
// __launch_bounds__(512, 1): min 1 block/CU -> 256-VGPR budget. (512,2) was
// a 128-reg cap (2 blocks/CU) that forced ~240MB/dispatch of scratch spill
// in rounds 3-5; grid==256==CU count so >1 block/CU never materializes.
// x-accumulator lives in LDS; force packed as bf16 pairs.
// ---------------------------------------------------------------------------

// phase-1 group g (0..15) covers kk = 2g, 2g+1  (kel = kk*32 + g4*8)
#define P1L(g, BUF) do {                                                      \
    BUF[0] = b0p[(2 * (g)) * 4];                                              \
    BUF[1] = b1p[(2 * (g)) * 4];                                              \
    BUF[2] = b0p[(2 * (g) + 1) * 4];                                          \
    BUF[3] = b1p[(2 * (g) + 1) * 4];                                          \
} while (0)

#define P1G(g, BUF) do {                                                      \
    _Pragma("unroll")                                                         \
    for (int t = 0; t < 2; ++t) {                                             \
        const int kel_ = (2 * (g) + t) * 32 + g4 * 8;                         \
        const s16x8 a_ = *(const s16x8*)&vb[m16 * DIMK + (kel_ ^ swz)];       \
        h0 = __builtin_amdgcn_mfma_f32_16x16x32_bf16(a_, BUF[2 * t], h0, 0, 0, 0);     \
        h1 = __builtin_amdgcn_mfma_f32_16x16x32_bf16(a_, BUF[2 * t + 1], h1, 0, 0, 0); \
    }                                                                         \
} while (0)

// phase-2 slot s (0..15): kk = s>>1, half = s&1, nt = half*4 + q
#define P2L(s, BUF) do {                                                      \
    _Pragma("unroll")                                                         \
    for (int q = 0; q < 4; ++q)                                               \
        BUF[q] = bwp[((((s) & 1) * 4 + q)) * 512 + ((s) >> 1) * 4];           \
} while (0)

#define P2G(s, BUF) do {                                                      \
    const int kel_ = ((s) >> 1) * 32 + g4 * 8;                                \
    const s16x8 a_ = *(const s16x8*)&gb[m16 * GPAD + kel_];                   \
    _Pragma("unroll")                                                         \
    for (int q = 0; q < 4; ++q)                                               \
        acc[((s) & 1) * 4 + q] = __builtin_amdgcn_mfma_f32_16x16x32_bf16(     \
            a_, BUF[q], acc[((s) & 1) * 4 + q], 0, 0, 0);                     \
} while (0)

__global__ __launch_bounds__(512, 1) void fr_kernel(
    const float* __restrict__ x_in, const float* __restrict__ v_in,
    const float* __restrict__ f_in, const ushort_t* __restrict__ Ut,
    const ushort_t* __restrict__ Wt, const int* __restrict__ steps_p,
    float* __restrict__ out) {
    __shared__ ushort_t vb[TROWS * DIMK];    // 32 KB, XOR-swizzled rows
    __shared__ ushort_t gb[TROWS * GPAD];    // 8.25 KB, padded rows
    __shared__ float    xs[TROWS * XPAD];    // 64.25 KB, x accumulator

    const int tid  = threadIdx.x;
    const int lane = tid & 63;
    const int wave = tid >> 6;          // 0..7
    const int m16  = lane & 15;
    const int g4   = lane >> 4;         // 0..3
    const int swz  = (m16 & 7) << 3;
    const int row0 = blockIdx.x * TROWS;
    const int n_acc = 3 * steps_p[0];

    // fragment ownership: i = nt*4 + r;  m = g4*4 + r;  n = wave*128 + nt*16 + m16
    float vreg[32];
    u32 fpk[16];
#pragma unroll
    for (int nt = 0; nt < 8; ++nt) {
        float fv[4];
#pragma unroll
        for (int r = 0; r < 4; ++r) {
            const int m = g4 * 4 + r;
            const int n = wave * 128 + nt * 16 + m16;
            const size_t gi = (size_t)(row0 + m) * DIMK + n;
            const float v0 = v_in[gi];
            vreg[nt * 4 + r] = v0;
            xs[m * XPAD + n] = x_in[gi] + (C1F * DTF) * v0;  // first x-substep folded
            fv[r] = f_in[gi];
            vb[m * DIMK + (n ^ ((m & 7) << 3))] = f2bf(v0);
        }
        fpk[nt * 2]     = pack2bf(fv[0], fv[1]);
        fpk[nt * 2 + 1] = pack2bf(fv[2], fv[3]);
    }

    // B-fragment pointers (16-byte per-lane loads)
    const s16x8* b0p = (const s16x8*)(Ut + (size_t)(wave * 32 + m16) * DIMK + g4 * 8);
    const s16x8* b1p = b0p + (16 * DIMK) / 8;
    const s16x8* bwp = (const s16x8*)(Wt + (size_t)(wave * 128 + m16) * RANKK + g4 * 8);
    const int n1a = wave * 32 + m16, n1b = n1a + 16;

    s16x8 pA[4], pB[4], pC[4], pD[4];
    P1L(0, pA); P1L(1, pB); P1L(2, pC); P1L(3, pD);
    __syncthreads();   // vb/xs ready (prefetch drains too; one-time cost)

    for (int j = 0; j < n_acc; ++j) {
        // ================= phase 1: h = v @ U ===============================
        f32x4 h0 = {0.f, 0.f, 0.f, 0.f}, h1 = {0.f, 0.f, 0.f, 0.f};
        P1G(0, pA);  P1L(4, pA);
        P1G(1, pB);  P1L(5, pB);
        P1G(2, pC);  P1L(6, pC);
        P1G(3, pD);  P1L(7, pD);
        P1G(4, pA);  P1L(8, pA);
        P1G(5, pB);  P1L(9, pB);
        P1G(6, pC);  P1L(10, pC);
        P1G(7, pD);  P1L(11, pD);
        P1G(8, pA);  P1L(12, pA);
        P1G(9, pB);  P1L(13, pB);
        P1G(10, pC); P1L(14, pC);
        P1G(11, pD); P1L(15, pD);
        P1G(12, pA); P2L(0, pA);   // cross-phase prefetch
        P1G(13, pB); P2L(1, pB);
        P1G(14, pC); P2L(2, pC);
        P1G(15, pD); P2L(3, pD);

        // g = h*h -> gb (padded rows)
#pragma unroll
        for (int r = 0; r < 4; ++r) {
            const int m = g4 * 4 + r;
            gb[m * GPAD + n1a] = f2bf(h0[r] * h0[r]);
            gb[m * GPAD + n1b] = f2bf(h1[r] * h1[r]);
        }
        __syncthreads();   // gb ready (drains P2 slot-0..3 prefetches)

        // ================= phase 2: Gamma = g @ W ===========================
        f32x4 acc[8];
#pragma unroll
        for (int nt = 0; nt < 8; ++nt) acc[nt] = (f32x4){0.f, 0.f, 0.f, 0.f};
        P2G(0, pA);  P2L(4, pA);
        P2G(1, pB);  P2L(5, pB);
        P2G(2, pC);  P2L(6, pC);
        P2G(3, pD);  P2L(7, pD);
        P2G(4, pA);  P2L(8, pA);
        P2G(5, pB);  P2L(9, pB);
        P2G(6, pC);  P2L(10, pC);
        P2G(7, pD);  P2L(11, pD);
        P2G(8, pA);  P2L(12, pA);
        P2G(9, pB);  P2L(13, pB);
        P2G(10, pC); P2L(14, pC);
        P2G(11, pD); P2L(15, pD);
        P2G(12, pA); P1L(0, pA);   // prefetch next accel's phase-1
        P2G(13, pB); P1L(1, pB);
        P2G(14, pC); P1L(2, pC);
        P2G(15, pD); P1L(3, pD);

        // ================= epilogue: v,x update + vb refresh ================
        const int ph = j - (j / 3) * 3;
        const float ddt = ((ph == 1) ? D2F : D1F) * DTF;
        const float cdt = ((ph == 2) ? ((j == n_acc - 1) ? C1F : THETAF) : C2F) * DTF;
#pragma unroll
        for (int nt = 0; nt < 8; ++nt) {
#pragma unroll
            for (int r = 0; r < 4; ++r) {
                const int i = nt * 4 + r;
                const int m = g4 * 4 + r;
                const int n = wave * 128 + nt * 16 + m16;
                const float fi = (r & 1) ? unpk_hi(fpk[nt * 2 + (r >> 1)])
                                         : unpk_lo(fpk[nt * 2 + (r >> 1)]);
                const float vn = vreg[i] + ddt * (fi - acc[nt][r]);
                vreg[i] = vn;
                xs[m * XPAD + n] += cdt * vn;   // thread-exclusive element
                vb[m * DIMK + (n ^ ((m & 7) << 3))] = f2bf(vn);
            }
        }
        __syncthreads();   // vb ready for next phase-1
    }

    // ---- write out: x then v, f32
    float* xo = out;
    float* vo = out + (size_t)BROWS * DIMK;
#pragma unroll
    for (int nt = 0; nt < 8; ++nt) {
#pragma unroll
        for (int r = 0; r < 4; ++r) {
            const int i = nt * 4 + r;
            const int m = g4 * 4 + r;
            const int n = wave * 128 + nt * 16 + m16;
            const size_t gi = (size_t)(row0 + m) * DIMK + n;
            xo[gi] = xs[m * XPAD + n];
            vo[gi] = vreg[i];
        }
    }
}

extern "C" void kernel_launch(void* const* d_in, const int* in_sizes, int n_in,
                              void* d_out, int out_size, void* d_ws, size_t ws_size,
                              hipStream_t stream) {
    const float* x = (const float*)d_in[0];
    const float* v = (const float*)d_in[1];
    const float* f = (const float*)d_in[2];
    const float* U = (const float*)d_in[3];   // [1024][256]
    const float* W = (const float*)d_in[4];   // [256][1024]
    const int* steps = (const int*)d_in[5];

    ushort_t* Ut = (ushort_t*)d_ws;                    // [256][1024] bf16
    ushort_t* Wt = Ut + (size_t)RANKK * DIMK;          // [1024][256] bf16
    float* out = (float*)d_out;

    fr_transpose_cast<<<(DIMK / 32) * (RANKK / 32), 256, 0, stream>>>(U, Ut, DIMK, RANKK);
    fr_transpose_cast<<<(RANKK / 32) * (DIMK / 32), 256, 0, stream>>>(W, Wt, RANKK, DIMK);
    fr_kernel<<<BROWS / TROWS, 512, 0, stream>>>(x, v, f, Ut, Wt, steps, out);
}

// Round 7
// 615.648 us; speedup vs baseline: 1.2727x; 1.2727x over previous
//
#include <hip/hip_runtime.h>

typedef unsigned short ushort_t;
typedef unsigned int u32;
typedef float f32x4 __attribute__((ext_vector_type(4)));
typedef short s16x8 __attribute__((ext_vector_type(8)));

#define BROWS 4096
#define DIMK  1024
#define RANKK 256
#define TROWS 16
#define GPAD  264      // gb row pad: 264 us = 528 B (16B-aligned rows)
#define XPAD  1028     // xs row pad: 1028 f32 (breaks 32-bank aliasing)

#define DTF 0.01f
#define THETAF 1.35120719195965763f
#define C1F    0.675603595979828816f   // THETA/2
#define C2F   (-0.175603595979828816f) // (1-THETA)/2
#define D1F    1.35120719195965763f    // THETA
#define D2F   (-1.70241438391931526f)  // 1-2*THETA

__device__ __forceinline__ ushort_t f2bf(float f) {
    unsigned u = __builtin_bit_cast(unsigned, f);
    return (ushort_t)((u + 0x7FFFu + ((u >> 16) & 1u)) >> 16);
}
__device__ __forceinline__ u32 pack2bf(float lo, float hi) {
    return (u32)f2bf(lo) | ((u32)f2bf(hi) << 16);
}
__device__ __forceinline__ float unpk_lo(u32 u) {
    return __builtin_bit_cast(float, u << 16);
}
__device__ __forceinline__ float unpk_hi(u32 u) {
    return __builtin_bit_cast(float, u & 0xFFFF0000u);
}

// MFMA with the accumulator PINNED to AGPRs ("a" constraint). The builtin's
// ext_vector return was being allocated in arch VGPRs; with the 128/128
// arch/AGPR split of the 256-reg budget (8-wave block), acc+h (40 regs) in
// the arch half forced ~240MB/dispatch scratch spill in rounds 3-6 while
// the AGPR half sat unused. Inline asm moves them where they belong.
__device__ __forceinline__ f32x4 mfma_agpr(s16x8 a, s16x8 b, f32x4 c) {
    asm("v_mfma_f32_16x16x32_bf16 %0, %1, %2, %0" : "+a"(c) : "v"(a), "v"(b));
    return c;
}

// ---------------------------------------------------------------------------
// Transpose + cast f32 -> bf16:  out[c][r] = bf16(in[r][c]),  in is [R][C].
// ---------------------------------------------------------------------------
__global__ void fr_transpose_cast(const float* __restrict__ in,
                                  ushort_t* __restrict__ out, int R, int C) {
    __shared__ float tile[32][33];
    int tiles_c = C >> 5;
    int tr = blockIdx.x / tiles_c;
    int tc = blockIdx.x % tiles_c;
    int tx = threadIdx.x & 31;
    int ty = threadIdx.x >> 5;
#pragma unroll
    for (int i = 0; i < 32; i += 8)
        tile[ty + i][tx] = in[(size_t)(tr * 32 + ty + i) * C + tc * 32 + tx];
    __syncthreads();
#pragma unroll
    for (int i = 0; i < 32; i += 8)
        out[(size_t)(tc * 32 + ty + i) * R + tr * 32 + tx] = f2bf(tile[tx][ty + i]);
}

// ---------------------------------------------------------------------------
// Fused Forest-Ruth integrator. Block = 16 rows, 512 threads (8 waves).
// Per-lane 16B B-fragment loads (L2-resident) with a two-buffer rotating
// register prefetch (8 loads in flight). Accumulators forced to AGPRs via
// inline-asm MFMA; arch-VGPR live set ~100 <= 128 -> no spill.
// x-accumulator lives in LDS; force packed as bf16 pairs.
// ---------------------------------------------------------------------------

// phase-1 group g (0..15) covers kk = 2g, 2g+1  (kel = kk*32 + g4*8)
#define P1L(g, BUF) do {                                                      \
    BUF[0] = b0p[(2 * (g)) * 4];                                              \
    BUF[1] = b1p[(2 * (g)) * 4];                                              \
    BUF[2] = b0p[(2 * (g) + 1) * 4];                                          \
    BUF[3] = b1p[(2 * (g) + 1) * 4];                                          \
} while (0)

#define P1G(g, BUF) do {                                                      \
    _Pragma("unroll")                                                         \
    for (int t = 0; t < 2; ++t) {                                             \
        const int kel_ = (2 * (g) + t) * 32 + g4 * 8;                         \
        const s16x8 a_ = *(const s16x8*)&vb[m16 * DIMK + (kel_ ^ swz)];       \
        h0 = mfma_agpr(a_, BUF[2 * t], h0);                                   \
        h1 = mfma_agpr(a_, BUF[2 * t + 1], h1);                               \
    }                                                                         \
} while (0)

// phase-2 slot s (0..15): kk = s>>1, half = s&1, nt = half*4 + q
#define P2L(s, BUF) do {                                                      \
    _Pragma("unroll")                                                         \
    for (int q = 0; q < 4; ++q)                                               \
        BUF[q] = bwp[((((s) & 1) * 4 + q)) * 512 + ((s) >> 1) * 4];           \
} while (0)

#define P2G(s, BUF) do {                                                      \
    const int kel_ = ((s) >> 1) * 32 + g4 * 8;                                \
    const s16x8 a_ = *(const s16x8*)&gb[m16 * GPAD + kel_];                   \
    _Pragma("unroll")                                                         \
    for (int q = 0; q < 4; ++q)                                               \
        acc[((s) & 1) * 4 + q] = mfma_agpr(a_, BUF[q], acc[((s) & 1) * 4 + q]); \
} while (0)

__global__ __launch_bounds__(512, 1) void fr_kernel(
    const float* __restrict__ x_in, const float* __restrict__ v_in,
    const float* __restrict__ f_in, const ushort_t* __restrict__ Ut,
    const ushort_t* __restrict__ Wt, const int* __restrict__ steps_p,
    float* __restrict__ out) {
    __shared__ ushort_t vb[TROWS * DIMK];    // 32 KB, XOR-swizzled rows
    __shared__ ushort_t gb[TROWS * GPAD];    // 8.25 KB, padded rows
    __shared__ float    xs[TROWS * XPAD];    // 64.25 KB, x accumulator

    const int tid  = threadIdx.x;
    const int lane = tid & 63;
    const int wave = tid >> 6;          // 0..7
    const int m16  = lane & 15;
    const int g4   = lane >> 4;         // 0..3
    const int swz  = (m16 & 7) << 3;
    const int row0 = blockIdx.x * TROWS;
    const int n_acc = 3 * steps_p[0];

    // fragment ownership: i = nt*4 + r;  m = g4*4 + r;  n = wave*128 + nt*16 + m16
    float vreg[32];
    u32 fpk[16];
#pragma unroll
    for (int nt = 0; nt < 8; ++nt) {
        float fv[4];
#pragma unroll
        for (int r = 0; r < 4; ++r) {
            const int m = g4 * 4 + r;
            const int n = wave * 128 + nt * 16 + m16;
            const size_t gi = (size_t)(row0 + m) * DIMK + n;
            const float v0 = v_in[gi];
            vreg[nt * 4 + r] = v0;
            xs[m * XPAD + n] = x_in[gi] + (C1F * DTF) * v0;  // first x-substep folded
            fv[r] = f_in[gi];
            vb[m * DIMK + (n ^ ((m & 7) << 3))] = f2bf(v0);
        }
        fpk[nt * 2]     = pack2bf(fv[0], fv[1]);
        fpk[nt * 2 + 1] = pack2bf(fv[2], fv[3]);
    }

    // B-fragment pointers (16-byte per-lane loads)
    const s16x8* b0p = (const s16x8*)(Ut + (size_t)(wave * 32 + m16) * DIMK + g4 * 8);
    const s16x8* b1p = b0p + (16 * DIMK) / 8;
    const s16x8* bwp = (const s16x8*)(Wt + (size_t)(wave * 128 + m16) * RANKK + g4 * 8);
    const int n1a = wave * 32 + m16, n1b = n1a + 16;

    s16x8 pA[4], pB[4];
    P1L(0, pA); P1L(1, pB);
    __syncthreads();   // vb/xs ready (drains prologue prefetch; one-time cost)

    for (int j = 0; j < n_acc; ++j) {
        // ================= phase 1: h = v @ U ===============================
        f32x4 h0 = {0.f, 0.f, 0.f, 0.f}, h1 = {0.f, 0.f, 0.f, 0.f};
        P1G(0, pA);  P1L(2, pA);
        P1G(1, pB);  P1L(3, pB);
        P1G(2, pA);  P1L(4, pA);
        P1G(3, pB);  P1L(5, pB);
        P1G(4, pA);  P1L(6, pA);
        P1G(5, pB);  P1L(7, pB);
        P1G(6, pA);  P1L(8, pA);
        P1G(7, pB);  P1L(9, pB);
        P1G(8, pA);  P1L(10, pA);
        P1G(9, pB);  P1L(11, pB);
        P1G(10, pA); P1L(12, pA);
        P1G(11, pB); P1L(13, pB);
        P1G(12, pA); P1L(14, pA);
        P1G(13, pB); P1L(15, pB);
        P1G(14, pA); P2L(0, pA);   // cross-phase prefetch
        P1G(15, pB); P2L(1, pB);

        // g = h*h -> gb (padded rows)
#pragma unroll
        for (int r = 0; r < 4; ++r) {
            const int m = g4 * 4 + r;
            gb[m * GPAD + n1a] = f2bf(h0[r] * h0[r]);
            gb[m * GPAD + n1b] = f2bf(h1[r] * h1[r]);
        }
        __syncthreads();   // gb ready (drains P2 slot-0/1 prefetch)

        // ================= phase 2: Gamma = g @ W ===========================
        f32x4 acc[8];
#pragma unroll
        for (int nt = 0; nt < 8; ++nt) acc[nt] = (f32x4){0.f, 0.f, 0.f, 0.f};
        P2G(0, pA);  P2L(2, pA);
        P2G(1, pB);  P2L(3, pB);
        P2G(2, pA);  P2L(4, pA);
        P2G(3, pB);  P2L(5, pB);
        P2G(4, pA);  P2L(6, pA);
        P2G(5, pB);  P2L(7, pB);
        P2G(6, pA);  P2L(8, pA);
        P2G(7, pB);  P2L(9, pB);
        P2G(8, pA);  P2L(10, pA);
        P2G(9, pB);  P2L(11, pB);
        P2G(10, pA); P2L(12, pA);
        P2G(11, pB); P2L(13, pB);
        P2G(12, pA); P2L(14, pA);
        P2G(13, pB); P2L(15, pB);
        P2G(14, pA); P1L(0, pA);   // prefetch next accel's phase-1
        P2G(15, pB); P1L(1, pB);

        // ================= epilogue: v,x update + vb refresh ================
        const int ph = j - (j / 3) * 3;
        const float ddt = ((ph == 1) ? D2F : D1F) * DTF;
        const float cdt = ((ph == 2) ? ((j == n_acc - 1) ? C1F : THETAF) : C2F) * DTF;
#pragma unroll
        for (int nt = 0; nt < 8; ++nt) {
#pragma unroll
            for (int r = 0; r < 4; ++r) {
                const int i = nt * 4 + r;
                const int m = g4 * 4 + r;
                const int n = wave * 128 + nt * 16 + m16;
                const float fi = (r & 1) ? unpk_hi(fpk[nt * 2 + (r >> 1)])
                                         : unpk_lo(fpk[nt * 2 + (r >> 1)]);
                const float vn = vreg[i] + ddt * (fi - acc[nt][r]);
                vreg[i] = vn;
                xs[m * XPAD + n] += cdt * vn;   // thread-exclusive element
                vb[m * DIMK + (n ^ ((m & 7) << 3))] = f2bf(vn);
            }
        }
        __syncthreads();   // vb ready for next phase-1
    }

    // ---- write out: x then v, f32
    float* xo = out;
    float* vo = out + (size_t)BROWS * DIMK;
#pragma unroll
    for (int nt = 0; nt < 8; ++nt) {
#pragma unroll
        for (int r = 0; r < 4; ++r) {
            const int i = nt * 4 + r;
            const int m = g4 * 4 + r;
            const int n = wave * 128 + nt * 16 + m16;
            const size_t gi = (size_t)(row0 + m) * DIMK + n;
            xo[gi] = xs[m * XPAD + n];
            vo[gi] = vreg[i];
        }
    }
}

extern "C" void kernel_launch(void* const* d_in, const int* in_sizes, int n_in,
                              void* d_out, int out_size, void* d_ws, size_t ws_size,
                              hipStream_t stream) {
    const float* x = (const float*)d_in[0];
    const float* v = (const float*)d_in[1];
    const float* f = (const float*)d_in[2];
    const float* U = (const float*)d_in[3];   // [1024][256]
    const float* W = (const float*)d_in[4];   // [256][1024]
    const int* steps = (const int*)d_in[5];

    ushort_t* Ut = (ushort_t*)d_ws;                    // [256][1024] bf16
    ushort_t* Wt = Ut + (size_t)RANKK * DIMK;          // [1024][256] bf16
    float* out = (float*)d_out;

    fr_transpose_cast<<<(DIMK / 32) * (RANKK / 32), 256, 0, stream>>>(U, Ut, DIMK, RANKK);
    fr_transpose_cast<<<(RANKK / 32) * (DIMK / 32), 256, 0, stream>>>(W, Wt, RANKK, DIMK);
    fr_kernel<<<BROWS / TROWS, 512, 0, stream>>>(x, v, f, Ut, Wt, steps, out);
}

// Round 8
// 425.332 us; speedup vs baseline: 1.8422x; 1.4475x over previous
//
#include <hip/hip_runtime.h>

typedef unsigned short ushort_t;
typedef unsigned int u32;
typedef float f32x4 __attribute__((ext_vector_type(4)));
typedef short s16x8 __attribute__((ext_vector_type(8)));

#define BROWS 4096
#define DIMK  1024
#define RANKK 256
#define TROWS 16

#define DTF 0.01f
#define THETAF 1.35120719195965763f
#define C1F    0.675603595979828816f   // THETA/2
#define C2F   (-0.175603595979828816f) // (1-THETA)/2
#define D1F    1.35120719195965763f    // THETA
#define D2F   (-1.70241438391931526f)  // 1-2*THETA

__device__ __forceinline__ ushort_t f2bf(float f) {
    unsigned u = __builtin_bit_cast(unsigned, f);
    return (ushort_t)((u + 0x7FFFu + ((u >> 16) & 1u)) >> 16);
}
__device__ __forceinline__ u32 pack2bf(float lo, float hi) {
    return (u32)f2bf(lo) | ((u32)f2bf(hi) << 16);
}
__device__ __forceinline__ float unpk_lo(u32 u) {
    return __builtin_bit_cast(float, u << 16);
}
__device__ __forceinline__ float unpk_hi(u32 u) {
    return __builtin_bit_cast(float, u & 0xFFFF0000u);
}

// Accumulators pinned to AGPRs (round-7 verified): keeps them out of the
// 128-reg arch budget the allocator insists on.
__device__ __forceinline__ f32x4 mfma_agpr(s16x8 a, s16x8 b, f32x4 c) {
    asm("v_mfma_f32_16x16x32_bf16 %0, %1, %2, %0" : "+a"(c) : "v"(a), "v"(b));
    return c;
}

// lgkm-only barrier: LDS producer/consumer sync WITHOUT the vmcnt(0) drain
// __syncthreads() emits -> global prefetches stay in flight across phases.
#define BAR() asm volatile("s_waitcnt lgkmcnt(0)\n\ts_barrier" ::: "memory")

// ---------------------------------------------------------------------------
// Packed B-operand layouts: one base pointer per lane, imm-offset dwordx4.
// Ut2[o]: o = ((w*16+m16)*32 + kk)*32 + g4*8 + e  -> U[k=kk*32+g4*8+e][n=w*16+m16]
// Wt2[o]: o = (((w*16+m16)*8 + s)*4 + nt)*32 + g4*8 + e
//                                       -> W[k=s*32+g4*8+e][n=w*64+nt*16+m16]
// ---------------------------------------------------------------------------
__global__ void fr_pack_u(const float* __restrict__ U, ushort_t* __restrict__ Ut2) {
    const int o = blockIdx.x * 256 + threadIdx.x;   // 0 .. 262143
    const int e = o & 7, g4 = (o >> 3) & 3, kk = (o >> 5) & 31;
    const int m16 = (o >> 10) & 15, w = (o >> 14) & 15;
    const int n = w * 16 + m16, k = kk * 32 + g4 * 8 + e;
    Ut2[o] = f2bf(U[k * RANKK + n]);
}
__global__ void fr_pack_w(const float* __restrict__ W, ushort_t* __restrict__ Wt2) {
    const int o = blockIdx.x * 256 + threadIdx.x;   // 0 .. 262143
    const int e = o & 7, g4 = (o >> 3) & 3, nt = (o >> 5) & 3;
    const int s = (o >> 7) & 7, m16 = (o >> 10) & 15, w = (o >> 14) & 15;
    const int n = w * 64 + nt * 16 + m16, k = s * 32 + g4 * 8 + e;
    Wt2[o] = f2bf(W[k * DIMK + n]);
}

// ---------------------------------------------------------------------------
// Fused Forest-Ruth integrator. Block = 16 rows, 1024 threads (16 waves,
// 4 waves/SIMD -> 50% occupancy TLP). Per wave: phase-1 one 16-col h-tile
// (32 MFMA), phase-2 four 16-col Gamma-tiles (32 MFMA). 4-buffer x 2-load
// register prefetch, 32 steps/accel (periodic), lgkm-only barriers.
// ---------------------------------------------------------------------------

#define L1(t, BUF) do {                                                       \
    BUF[0] = *(const s16x8*)(up + (2 * (t)) * 32);                            \
    BUF[1] = *(const s16x8*)(up + (2 * (t) + 1) * 32);                        \
} while (0)

#define G1(t, BUF) do {                                                       \
    { const s16x8 a_ = *(const s16x8*)&vb[m16 * DIMK + (((2*(t))*32 + g4*8) ^ swz)];   \
      h0 = mfma_agpr(a_, BUF[0], h0); }                                       \
    { const s16x8 a_ = *(const s16x8*)&vb[m16 * DIMK + (((2*(t)+1)*32 + g4*8) ^ swz)]; \
      h0 = mfma_agpr(a_, BUF[1], h0); }                                       \
} while (0)

#define L2(u, BUF) do {                                                       \
    BUF[0] = *(const s16x8*)(wp + ((u) >> 1) * 128 + (((u) & 1) * 2) * 32);   \
    BUF[1] = *(const s16x8*)(wp + ((u) >> 1) * 128 + (((u) & 1) * 2 + 1) * 32);\
} while (0)

#define G2(u, A2, BUF) do {                                                   \
    acc[((u) & 1) * 2]     = mfma_agpr(A2, BUF[0], acc[((u) & 1) * 2]);       \
    acc[((u) & 1) * 2 + 1] = mfma_agpr(A2, BUF[1], acc[((u) & 1) * 2 + 1]);   \
} while (0)

#define ARD(s) (*(const s16x8*)&gb[m16 * RANKK + (((s) * 32 + g4 * 8) ^ swz)])

__global__ __launch_bounds__(1024) void fr_kernel(
    const float* __restrict__ x_in, const float* __restrict__ v_in,
    const float* __restrict__ f_in, const ushort_t* __restrict__ Ut2,
    const ushort_t* __restrict__ Wt2, const int* __restrict__ steps_p,
    float* __restrict__ out) {
    __shared__ ushort_t vb[TROWS * DIMK];    // 32 KB, bf16 v, XOR-swizzled rows
    __shared__ ushort_t gb[TROWS * RANKK];   // 8 KB, bf16 h^2, XOR-swizzled rows
    __shared__ float    xs[TROWS * DIMK];    // 64 KB, x0 (parked; no in-loop use)
    __shared__ u32      fb[8 * 1024];        // 32 KB, force as bf16 pairs

    const int tid  = threadIdx.x;
    const int lane = tid & 63;
    const int wave = tid >> 6;          // 0..15
    const int m16  = lane & 15;
    const int g4   = lane >> 4;         // 0..3
    const int swz  = (m16 & 7) << 3;
    const int row0 = blockIdx.x * TROWS;
    const int n_acc = 3 * steps_p[0];

    // thread owns 16 elems: i = nt*4 + r; m = g4*4 + r; n = wave*64 + nt*16 + m16
    float vreg[16], xdelta[16];
#pragma unroll
    for (int nt = 0; nt < 4; ++nt) {
        float fv[4];
#pragma unroll
        for (int r = 0; r < 4; ++r) {
            const int m = g4 * 4 + r;
            const int n = wave * 64 + nt * 16 + m16;
            const size_t gi = (size_t)(row0 + m) * DIMK + n;
            const float v0 = v_in[gi];
            vreg[nt * 4 + r]   = v0;
            xdelta[nt * 4 + r] = (C1F * DTF) * v0;   // first x-substep folded
            xs[m * DIMK + n]   = x_in[gi];
            fv[r] = f_in[gi];
            vb[m * DIMK + (n ^ ((m & 7) << 3))] = f2bf(v0);
        }
        fb[(nt * 2 + 0) * 1024 + tid] = pack2bf(fv[0], fv[1]);
        fb[(nt * 2 + 1) * 1024 + tid] = pack2bf(fv[2], fv[3]);
    }

    // single per-lane base pointers (all loads are imm-offset dwordx4)
    const ushort_t* up = Ut2 + (wave * 16 + m16) * 1024 + g4 * 8;
    const ushort_t* wp = Wt2 + (wave * 16 + m16) * 1024 + g4 * 8;

    s16x8 bA[2], bB[2], bC[2], bD[2];
    L1(0, bA); L1(1, bB); L1(2, bC); L1(3, bD);
    __syncthreads();   // one-time full drain: vb/xs/fb + prologue prefetch

    f32x4 acc[4];
    for (int j = 0; j < n_acc; ++j) {
        // ========== phase 1: h = v @ U (this wave: col-tile `wave`) =========
        f32x4 h0 = {0.f, 0.f, 0.f, 0.f};
        G1(0, bA);  L1(4, bA);
        G1(1, bB);  L1(5, bB);
        G1(2, bC);  L1(6, bC);
        G1(3, bD);  L1(7, bD);
        G1(4, bA);  L1(8, bA);
        G1(5, bB);  L1(9, bB);
        G1(6, bC);  L1(10, bC);
        G1(7, bD);  L1(11, bD);
        G1(8, bA);  L1(12, bA);
        G1(9, bB);  L1(13, bB);
        G1(10, bC); L1(14, bC);
        G1(11, bD); L1(15, bD);
        G1(12, bA); L2(0, bA);   // cross-phase prefetch
        G1(13, bB); L2(1, bB);
        G1(14, bC); L2(2, bC);
        G1(15, bD); L2(3, bD);

        // g = h*h -> gb (col n1 = wave*16 + m16)
        {
            const int n1 = wave * 16 + m16;
#pragma unroll
            for (int r = 0; r < 4; ++r) {
                const int m = g4 * 4 + r;
                gb[m * RANKK + (n1 ^ ((m & 7) << 3))] = f2bf(h0[r] * h0[r]);
            }
        }
        BAR();   // gb ready; prefetches remain in flight

        // ========== phase 2: Gamma = g @ W (4 col-tiles per wave) ===========
#pragma unroll
        for (int q = 0; q < 4; ++q) acc[q] = (f32x4){0.f, 0.f, 0.f, 0.f};
        { const s16x8 a0 = ARD(0); G2(0, a0, bA); L2(4, bA);  G2(1, a0, bB); L2(5, bB); }
        { const s16x8 a1 = ARD(1); G2(2, a1, bC); L2(6, bC);  G2(3, a1, bD); L2(7, bD); }
        { const s16x8 a2 = ARD(2); G2(4, a2, bA); L2(8, bA);  G2(5, a2, bB); L2(9, bB); }
        { const s16x8 a3 = ARD(3); G2(6, a3, bC); L2(10, bC); G2(7, a3, bD); L2(11, bD); }
        { const s16x8 a4 = ARD(4); G2(8, a4, bA); L2(12, bA); G2(9, a4, bB); L2(13, bB); }
        { const s16x8 a5 = ARD(5); G2(10, a5, bC); L2(14, bC); G2(11, a5, bD); L2(15, bD); }
        { const s16x8 a6 = ARD(6); G2(12, a6, bA); L1(0, bA);  G2(13, a6, bB); L1(1, bB); }
        { const s16x8 a7 = ARD(7); G2(14, a7, bC); L1(2, bC);  G2(15, a7, bD); L1(3, bD); }

        // ========== epilogue: v update, x-delta, vb refresh =================
        const int ph = j - (j / 3) * 3;
        const float ddt = ((ph == 1) ? D2F : D1F) * DTF;
        const float cdt = ((ph == 2) ? ((j == n_acc - 1) ? C1F : THETAF) : C2F) * DTF;
#pragma unroll
        for (int nt = 0; nt < 4; ++nt) {
#pragma unroll
            for (int r = 0; r < 4; ++r) {
                const int i = nt * 4 + r;
                const int m = g4 * 4 + r;
                const int n = wave * 64 + nt * 16 + m16;
                const u32 pk = fb[(nt * 2 + (r >> 1)) * 1024 + tid];
                const float fi = (r & 1) ? unpk_hi(pk) : unpk_lo(pk);
                const float vn = vreg[i] + ddt * (fi - acc[nt][r]);
                vreg[i] = vn;
                xdelta[i] += cdt * vn;
                vb[m * DIMK + (n ^ ((m & 7) << 3))] = f2bf(vn);
            }
        }
        BAR();   // vb ready for next phase-1
    }

    // ---- write out: x = x0 + delta, then v
    float* xo = out;
    float* vo = out + (size_t)BROWS * DIMK;
#pragma unroll
    for (int nt = 0; nt < 4; ++nt) {
#pragma unroll
        for (int r = 0; r < 4; ++r) {
            const int i = nt * 4 + r;
            const int m = g4 * 4 + r;
            const int n = wave * 64 + nt * 16 + m16;
            const size_t gi = (size_t)(row0 + m) * DIMK + n;
            xo[gi] = xs[m * DIMK + n] + xdelta[i];
            vo[gi] = vreg[i];
        }
    }
}

extern "C" void kernel_launch(void* const* d_in, const int* in_sizes, int n_in,
                              void* d_out, int out_size, void* d_ws, size_t ws_size,
                              hipStream_t stream) {
    const float* x = (const float*)d_in[0];
    const float* v = (const float*)d_in[1];
    const float* f = (const float*)d_in[2];
    const float* U = (const float*)d_in[3];   // [1024][256]
    const float* W = (const float*)d_in[4];   // [256][1024]
    const int* steps = (const int*)d_in[5];

    ushort_t* Ut2 = (ushort_t*)d_ws;                     // packed bf16, 512 KB
    ushort_t* Wt2 = Ut2 + (size_t)RANKK * DIMK;          // packed bf16, 512 KB
    float* out = (float*)d_out;

    fr_pack_u<<<1024, 256, 0, stream>>>(U, Ut2);
    fr_pack_w<<<1024, 256, 0, stream>>>(W, Wt2);
    fr_kernel<<<BROWS / TROWS, 1024, 0, stream>>>(x, v, f, Ut2, Wt2, steps, out);
}

// Round 9
// 420.677 us; speedup vs baseline: 1.8626x; 1.0111x over previous
//
#include <hip/hip_runtime.h>

typedef unsigned short ushort_t;
typedef unsigned int u32;
typedef float f32x4 __attribute__((ext_vector_type(4)));
typedef short s16x8 __attribute__((ext_vector_type(8)));

#define BROWS 4096
#define DIMK  1024
#define RANKK 256
#define TROWS 16

#define DTF 0.01f
#define THETAF 1.35120719195965763f
#define C1F    0.675603595979828816f   // THETA/2
#define C2F   (-0.175603595979828816f) // (1-THETA)/2
#define D1F    1.35120719195965763f    // THETA
#define D2F   (-1.70241438391931526f)  // 1-2*THETA

__device__ __forceinline__ ushort_t f2bf(float f) {
    unsigned u = __builtin_bit_cast(unsigned, f);
    return (ushort_t)((u + 0x7FFFu + ((u >> 16) & 1u)) >> 16);
}
__device__ __forceinline__ u32 pack2bf(float lo, float hi) {
    return (u32)f2bf(lo) | ((u32)f2bf(hi) << 16);
}
__device__ __forceinline__ float unpk_lo(u32 u) {
    return __builtin_bit_cast(float, u << 16);
}
__device__ __forceinline__ float unpk_hi(u32 u) {
    return __builtin_bit_cast(float, u & 0xFFFF0000u);
}

// Accumulators pinned to AGPRs (round-7 verified): keeps them out of the
// arch-VGPR budget.
__device__ __forceinline__ f32x4 mfma_agpr(s16x8 a, s16x8 b, f32x4 c) {
    asm("v_mfma_f32_16x16x32_bf16 %0, %1, %2, %0" : "+a"(c) : "v"(a), "v"(b));
    return c;
}

// lgkm-only barrier: LDS producer/consumer sync WITHOUT the vmcnt(0) drain
// __syncthreads() emits -> global prefetches stay in flight across phases.
#define BAR() asm volatile("s_waitcnt lgkmcnt(0)\n\ts_barrier" ::: "memory")

// ---------------------------------------------------------------------------
// Packed B-operand layouts: one base pointer per lane, imm-offset dwordx4.
// Ut2[o]: o = ((w*16+m16)*32 + kk)*32 + g4*8 + e  -> U[k=kk*32+g4*8+e][n=w*16+m16]
// Wt2[o]: o = (((w*16+m16)*8 + s)*4 + nt)*32 + g4*8 + e
//                                       -> W[k=s*32+g4*8+e][n=w*64+nt*16+m16]
// ---------------------------------------------------------------------------
__global__ void fr_pack_u(const float* __restrict__ U, ushort_t* __restrict__ Ut2) {
    const int o = blockIdx.x * 256 + threadIdx.x;   // 0 .. 262143
    const int e = o & 7, g4 = (o >> 3) & 3, kk = (o >> 5) & 31;
    const int m16 = (o >> 10) & 15, w = (o >> 14) & 15;
    const int n = w * 16 + m16, k = kk * 32 + g4 * 8 + e;
    Ut2[o] = f2bf(U[k * RANKK + n]);
}
__global__ void fr_pack_w(const float* __restrict__ W, ushort_t* __restrict__ Wt2) {
    const int o = blockIdx.x * 256 + threadIdx.x;   // 0 .. 262143
    const int e = o & 7, g4 = (o >> 3) & 3, nt = (o >> 5) & 3;
    const int s = (o >> 7) & 7, m16 = (o >> 10) & 15, w = (o >> 14) & 15;
    const int n = w * 64 + nt * 16 + m16, k = s * 32 + g4 * 8 + e;
    Wt2[o] = f2bf(W[k * DIMK + n]);
}

// ---------------------------------------------------------------------------
// Fused Forest-Ruth integrator. Block = 16 rows, 1024 threads (16 waves,
// 4 waves/SIMD). Per wave: phase-1 one 16-col h-tile (32 MFMA), phase-2
// four 16-col Gamma-tiles (32 MFMA). 4-buffer x 2-load register prefetch,
// lgkm-only barriers.
// __launch_bounds__(1024, 4): min 4 waves/EU. LDS (136KB) already caps us
// at 1 block/CU = 4 waves/EU, but WITHOUT the hint the allocator targeted
// 8 waves/EU and capped arch VGPRs at 64 -> ~75MB/dispatch scratch spill
// (round 8: FETCH 147MB, WRITE 106MB). The hint raises the cap to 128
// (512-reg/SIMD pool / 4 waves); live set ~80 arch + 20 AGPR -> no spill.
// ---------------------------------------------------------------------------

#define L1(t, BUF) do {                                                       \
    BUF[0] = *(const s16x8*)(up + (2 * (t)) * 32);                            \
    BUF[1] = *(const s16x8*)(up + (2 * (t) + 1) * 32);                        \
} while (0)

#define G1(t, BUF) do {                                                       \
    { const s16x8 a_ = *(const s16x8*)&vb[m16 * DIMK + (((2*(t))*32 + g4*8) ^ swz)];   \
      h0 = mfma_agpr(a_, BUF[0], h0); }                                       \
    { const s16x8 a_ = *(const s16x8*)&vb[m16 * DIMK + (((2*(t)+1)*32 + g4*8) ^ swz)]; \
      h0 = mfma_agpr(a_, BUF[1], h0); }                                       \
} while (0)

#define L2(u, BUF) do {                                                       \
    BUF[0] = *(const s16x8*)(wp + ((u) >> 1) * 128 + (((u) & 1) * 2) * 32);   \
    BUF[1] = *(const s16x8*)(wp + ((u) >> 1) * 128 + (((u) & 1) * 2 + 1) * 32);\
} while (0)

#define G2(u, A2, BUF) do {                                                   \
    acc[((u) & 1) * 2]     = mfma_agpr(A2, BUF[0], acc[((u) & 1) * 2]);       \
    acc[((u) & 1) * 2 + 1] = mfma_agpr(A2, BUF[1], acc[((u) & 1) * 2 + 1]);   \
} while (0)

#define ARD(s) (*(const s16x8*)&gb[m16 * RANKK + (((s) * 32 + g4 * 8) ^ swz)])

__global__ __launch_bounds__(1024, 4) void fr_kernel(
    const float* __restrict__ x_in, const float* __restrict__ v_in,
    const float* __restrict__ f_in, const ushort_t* __restrict__ Ut2,
    const ushort_t* __restrict__ Wt2, const int* __restrict__ steps_p,
    float* __restrict__ out) {
    __shared__ ushort_t vb[TROWS * DIMK];    // 32 KB, bf16 v, XOR-swizzled rows
    __shared__ ushort_t gb[TROWS * RANKK];   // 8 KB, bf16 h^2, XOR-swizzled rows
    __shared__ float    xs[TROWS * DIMK];    // 64 KB, x0 (parked; no in-loop use)
    __shared__ u32      fb[8 * 1024];        // 32 KB, force as bf16 pairs

    const int tid  = threadIdx.x;
    const int lane = tid & 63;
    const int wave = tid >> 6;          // 0..15
    const int m16  = lane & 15;
    const int g4   = lane >> 4;         // 0..3
    const int swz  = (m16 & 7) << 3;
    const int row0 = blockIdx.x * TROWS;
    const int n_acc = 3 * steps_p[0];

    // thread owns 16 elems: i = nt*4 + r; m = g4*4 + r; n = wave*64 + nt*16 + m16
    float vreg[16], xdelta[16];
#pragma unroll
    for (int nt = 0; nt < 4; ++nt) {
        float fv[4];
#pragma unroll
        for (int r = 0; r < 4; ++r) {
            const int m = g4 * 4 + r;
            const int n = wave * 64 + nt * 16 + m16;
            const size_t gi = (size_t)(row0 + m) * DIMK + n;
            const float v0 = v_in[gi];
            vreg[nt * 4 + r]   = v0;
            xdelta[nt * 4 + r] = (C1F * DTF) * v0;   // first x-substep folded
            xs[m * DIMK + n]   = x_in[gi];
            fv[r] = f_in[gi];
            vb[m * DIMK + (n ^ ((m & 7) << 3))] = f2bf(v0);
        }
        fb[(nt * 2 + 0) * 1024 + tid] = pack2bf(fv[0], fv[1]);
        fb[(nt * 2 + 1) * 1024 + tid] = pack2bf(fv[2], fv[3]);
    }

    // single per-lane base pointers (all loads are imm-offset dwordx4)
    const ushort_t* up = Ut2 + (wave * 16 + m16) * 1024 + g4 * 8;
    const ushort_t* wp = Wt2 + (wave * 16 + m16) * 1024 + g4 * 8;

    s16x8 bA[2], bB[2], bC[2], bD[2];
    L1(0, bA); L1(1, bB); L1(2, bC); L1(3, bD);
    __syncthreads();   // one-time full drain: vb/xs/fb + prologue prefetch

    f32x4 acc[4];
    for (int j = 0; j < n_acc; ++j) {
        // ========== phase 1: h = v @ U (this wave: col-tile `wave`) =========
        f32x4 h0 = {0.f, 0.f, 0.f, 0.f};
        G1(0, bA);  L1(4, bA);
        G1(1, bB);  L1(5, bB);
        G1(2, bC);  L1(6, bC);
        G1(3, bD);  L1(7, bD);
        G1(4, bA);  L1(8, bA);
        G1(5, bB);  L1(9, bB);
        G1(6, bC);  L1(10, bC);
        G1(7, bD);  L1(11, bD);
        G1(8, bA);  L1(12, bA);
        G1(9, bB);  L1(13, bB);
        G1(10, bC); L1(14, bC);
        G1(11, bD); L1(15, bD);
        G1(12, bA); L2(0, bA);   // cross-phase prefetch
        G1(13, bB); L2(1, bB);
        G1(14, bC); L2(2, bC);
        G1(15, bD); L2(3, bD);

        // g = h*h -> gb (col n1 = wave*16 + m16)
        {
            const int n1 = wave * 16 + m16;
#pragma unroll
            for (int r = 0; r < 4; ++r) {
                const int m = g4 * 4 + r;
                gb[m * RANKK + (n1 ^ ((m & 7) << 3))] = f2bf(h0[r] * h0[r]);
            }
        }
        BAR();   // gb ready; prefetches remain in flight

        // ========== phase 2: Gamma = g @ W (4 col-tiles per wave) ===========
#pragma unroll
        for (int q = 0; q < 4; ++q) acc[q] = (f32x4){0.f, 0.f, 0.f, 0.f};
        { const s16x8 a0 = ARD(0); G2(0, a0, bA); L2(4, bA);  G2(1, a0, bB); L2(5, bB); }
        { const s16x8 a1 = ARD(1); G2(2, a1, bC); L2(6, bC);  G2(3, a1, bD); L2(7, bD); }
        { const s16x8 a2 = ARD(2); G2(4, a2, bA); L2(8, bA);  G2(5, a2, bB); L2(9, bB); }
        { const s16x8 a3 = ARD(3); G2(6, a3, bC); L2(10, bC); G2(7, a3, bD); L2(11, bD); }
        { const s16x8 a4 = ARD(4); G2(8, a4, bA); L2(12, bA); G2(9, a4, bB); L2(13, bB); }
        { const s16x8 a5 = ARD(5); G2(10, a5, bC); L2(14, bC); G2(11, a5, bD); L2(15, bD); }
        { const s16x8 a6 = ARD(6); G2(12, a6, bA); L1(0, bA);  G2(13, a6, bB); L1(1, bB); }
        { const s16x8 a7 = ARD(7); G2(14, a7, bC); L1(2, bC);  G2(15, a7, bD); L1(3, bD); }

        // ========== epilogue: v update, x-delta, vb refresh =================
        const int ph = j - (j / 3) * 3;
        const float ddt = ((ph == 1) ? D2F : D1F) * DTF;
        const float cdt = ((ph == 2) ? ((j == n_acc - 1) ? C1F : THETAF) : C2F) * DTF;
#pragma unroll
        for (int nt = 0; nt < 4; ++nt) {
#pragma unroll
            for (int r = 0; r < 4; ++r) {
                const int i = nt * 4 + r;
                const int m = g4 * 4 + r;
                const int n = wave * 64 + nt * 16 + m16;
                const u32 pk = fb[(nt * 2 + (r >> 1)) * 1024 + tid];
                const float fi = (r & 1) ? unpk_hi(pk) : unpk_lo(pk);
                const float vn = vreg[i] + ddt * (fi - acc[nt][r]);
                vreg[i] = vn;
                xdelta[i] += cdt * vn;
                vb[m * DIMK + (n ^ ((m & 7) << 3))] = f2bf(vn);
            }
        }
        BAR();   // vb ready for next phase-1
    }

    // ---- write out: x = x0 + delta, then v
    float* xo = out;
    float* vo = out + (size_t)BROWS * DIMK;
#pragma unroll
    for (int nt = 0; nt < 4; ++nt) {
#pragma unroll
        for (int r = 0; r < 4; ++r) {
            const int i = nt * 4 + r;
            const int m = g4 * 4 + r;
            const int n = wave * 64 + nt * 16 + m16;
            const size_t gi = (size_t)(row0 + m) * DIMK + n;
            xo[gi] = xs[m * DIMK + n] + xdelta[i];
            vo[gi] = vreg[i];
        }
    }
}

extern "C" void kernel_launch(void* const* d_in, const int* in_sizes, int n_in,
                              void* d_out, int out_size, void* d_ws, size_t ws_size,
                              hipStream_t stream) {
    const float* x = (const float*)d_in[0];
    const float* v = (const float*)d_in[1];
    const float* f = (const float*)d_in[2];
    const float* U = (const float*)d_in[3];   // [1024][256]
    const float* W = (const float*)d_in[4];   // [256][1024]
    const int* steps = (const int*)d_in[5];

    ushort_t* Ut2 = (ushort_t*)d_ws;                     // packed bf16, 512 KB
    ushort_t* Wt2 = Ut2 + (size_t)RANKK * DIMK;          // packed bf16, 512 KB
    float* out = (float*)d_out;

    fr_pack_u<<<1024, 256, 0, stream>>>(U, Ut2);
    fr_pack_w<<<1024, 256, 0, stream>>>(W, Wt2);
    fr_kernel<<<BROWS / TROWS, 1024, 0, stream>>>(x, v, f, Ut2, Wt2, steps, out);
}